// Round 1
// baseline (766.621 us; speedup 1.0000x reference)
//
#include <hip/hip_runtime.h>
#include <hip/hip_bf16.h>
#include <math.h>

#define NNODES 50000
#define NEDGES 800000

typedef short s8v __attribute__((ext_vector_type(8)));
typedef float f4v __attribute__((ext_vector_type(4)));
using bf16 = __hip_bfloat16;

static __device__ __forceinline__ float bf2f(unsigned int u16) {
    union { unsigned int i; float f; } c; c.i = u16 << 16; return c.f;
}

// ---------------- small utility kernels ----------------

__global__ void k_f2b(const float* __restrict__ src, bf16* __restrict__ dst, int n) {
    int i = blockIdx.x * blockDim.x + threadIdx.x;
    if (i < n) dst[i] = __float2bfloat16(src[i]);
}

__global__ void k_degree(const int* __restrict__ ei, int* __restrict__ out_cnt, int* __restrict__ in_cnt) {
    int e = blockIdx.x * blockDim.x + threadIdx.x;
    if (e < NEDGES) {
        atomicAdd(&out_cnt[ei[e]], 1);
        atomicAdd(&in_cnt[ei[NEDGES + e]], 1);
    }
}

// single-block exclusive scan of in_cnt -> offsets[N+1]; also seeds cursor
__global__ void k_scan(const int* __restrict__ in_cnt, int* __restrict__ offsets, int* __restrict__ cursor) {
    __shared__ int s[1024];
    const int T = 1024, CH = (NNODES + T - 1) / T;
    int t = threadIdx.x;
    int beg = t * CH, end = min(beg + CH, NNODES);
    int sum = 0;
    for (int i = beg; i < end; ++i) sum += in_cnt[i];
    s[t] = sum;
    __syncthreads();
    for (int off = 1; off < T; off <<= 1) {
        int v = (t >= off) ? s[t - off] : 0;
        __syncthreads();
        s[t] += v;
        __syncthreads();
    }
    int base = (t > 0) ? s[t - 1] : 0;
    for (int i = beg; i < end; ++i) {
        offsets[i] = base; cursor[i] = base;
        base += in_cnt[i];
    }
    if (t == T - 1) offsets[NNODES] = s[T - 1];
}

// counting-sort scatter: bucket edges by destination, precompute norm
__global__ void k_scatter(const int* __restrict__ ei, const int* __restrict__ out_cnt,
                          const int* __restrict__ in_cnt, int* __restrict__ cursor,
                          int* __restrict__ src_sorted, float* __restrict__ norm_sorted) {
    int e = blockIdx.x * blockDim.x + threadIdx.x;
    if (e < NEDGES) {
        int r = ei[e], c = ei[NEDGES + e];
        int p = atomicAdd(&cursor[c], 1);
        src_sorted[p] = r;
        norm_sorted[p] = rsqrtf((float)out_cnt[r] * (float)in_cnt[c]);
    }
}

// ---------------- aggregation: one wave per destination node ----------------

template<int D>
__global__ void k_aggregate(const bf16* __restrict__ xw, const int* __restrict__ offsets,
                            const int* __restrict__ src_sorted, const float* __restrict__ norm_sorted,
                            float* __restrict__ agg) {
    const int VPL = D / 64; // floats per lane: 4 (D=256) or 2 (D=128)
    int lane = threadIdx.x & 63;
    int v = blockIdx.x * (blockDim.x >> 6) + (threadIdx.x >> 6);
    if (v >= NNODES) return;
    float acc[VPL];
#pragma unroll
    for (int c = 0; c < VPL; ++c) acc[c] = 0.f;
    int beg = offsets[v], end = offsets[v + 1];
    for (int j = beg; j < end; ++j) {
        int s = src_sorted[j];
        float w = norm_sorted[j];
        const unsigned short* p = (const unsigned short*)(xw + (size_t)s * D) + lane * VPL;
        if (VPL == 4) {
            uint2 q = *(const uint2*)p;
            acc[0] += w * bf2f(q.x & 0xffffu);
            acc[1] += w * bf2f(q.x >> 16);
            acc[2] += w * bf2f(q.y & 0xffffu);
            acc[3] += w * bf2f(q.y >> 16);
        } else {
            unsigned int q = *(const unsigned int*)p;
            acc[0] += w * bf2f(q & 0xffffu);
            acc[1] += w * bf2f(q >> 16);
        }
    }
    float* o = agg + (size_t)v * D + lane * VPL;
#pragma unroll
    for (int c = 0; c < VPL; ++c) o[c] = acc[c];
}

// ---------------- MFMA GEMM: [N,256] @ [256,C], 64x64 tile, 4 waves ----------------
// EPI: 0 -> store bf16 (xw); 1 -> +agg+bias, relu -> bf16; 2 -> +agg+bias, sigmoid -> float
template<int C, int EPI, bool A_BF16>
__global__ __launch_bounds__(256) void k_gemm(const void* __restrict__ Aptr, const bf16* __restrict__ B,
                                              const float* __restrict__ agg, const float* __restrict__ bias,
                                              void* __restrict__ Out) {
    __shared__ bf16 As[64][40];   // rows x k (pad 32->40 to spread banks)
    __shared__ bf16 Bs[64][40];   // Bs[n][k] (transposed at staging)
    const int R = NNODES;
    int t = threadIdx.x;
    int wave = t >> 6, lane = t & 63;
    int r0 = blockIdx.x * 64;
    int n0 = blockIdx.y * 64;

    f4v acc[4];
#pragma unroll
    for (int i = 0; i < 4; ++i) acc[i] = (f4v){0.f, 0.f, 0.f, 0.f};

    int arow = t >> 2, aseg = t & 3;  // 64 rows x 4 segments of 8 bf16
    int bn = t & 63, bkseg = t >> 6;  // 64 cols x 4 ksegs of 8

    for (int k0 = 0; k0 < 256; k0 += 32) {
        { // stage A tile (convert fp32->bf16 on the fly for layer-1 input)
            union { bf16 h[8]; uint4 v; } u;
            int gr = r0 + arow;
            if (gr < R) {
                if (A_BF16) {
                    const bf16* Ab = (const bf16*)Aptr;
                    u.v = *(const uint4*)(Ab + (size_t)gr * 256 + k0 + aseg * 8);
                } else {
                    const float* Af = (const float*)Aptr;
                    const float4* p = (const float4*)(Af + (size_t)gr * 256 + k0 + aseg * 8);
                    float4 f0 = p[0], f1 = p[1];
                    u.h[0] = __float2bfloat16(f0.x); u.h[1] = __float2bfloat16(f0.y);
                    u.h[2] = __float2bfloat16(f0.z); u.h[3] = __float2bfloat16(f0.w);
                    u.h[4] = __float2bfloat16(f1.x); u.h[5] = __float2bfloat16(f1.y);
                    u.h[6] = __float2bfloat16(f1.z); u.h[7] = __float2bfloat16(f1.w);
                }
            } else {
                u.v = (uint4){0, 0, 0, 0};
            }
            *(uint4*)&As[arow][aseg * 8] = u.v;
        }
        { // stage B tile transposed: Bs[n][k]; global reads coalesced across threads per j
            union { bf16 h[8]; uint4 v; } u;
#pragma unroll
            for (int j = 0; j < 8; ++j)
                u.h[j] = B[(size_t)(k0 + bkseg * 8 + j) * C + n0 + bn];
            *(uint4*)&Bs[bn][bkseg * 8] = u.v;
        }
        __syncthreads();
        int m = wave * 16 + (lane & 15);
        int kq = (lane >> 4) * 8;
        s8v a = *(const s8v*)&As[m][kq];
#pragma unroll
        for (int nt = 0; nt < 4; ++nt) {
            s8v b = *(const s8v*)&Bs[nt * 16 + (lane & 15)][kq];
            acc[nt] = __builtin_amdgcn_mfma_f32_16x16x32_bf16(a, b, acc[nt], 0, 0, 0);
        }
        __syncthreads();
    }
    // epilogue: C/D layout col=lane&15, row=(lane>>4)*4+reg  [m89/m91-verified]
#pragma unroll
    for (int nt = 0; nt < 4; ++nt) {
#pragma unroll
        for (int r = 0; r < 4; ++r) {
            int grow = r0 + wave * 16 + (lane >> 4) * 4 + r;
            int gcol = n0 + nt * 16 + (lane & 15);
            if (grow < R) {
                float v = acc[nt][r];
                if (EPI == 0) {
                    ((bf16*)Out)[(size_t)grow * C + gcol] = __float2bfloat16(v);
                } else {
                    v += agg[(size_t)grow * C + gcol] + bias[gcol];
                    if (EPI == 1) {
                        v = fmaxf(v, 0.f);
                        ((bf16*)Out)[(size_t)grow * C + gcol] = __float2bfloat16(v);
                    } else {
                        v = 1.f / (1.f + expf(-v));
                        ((float*)Out)[(size_t)grow * C + gcol] = v;
                    }
                }
            }
        }
    }
}

// ---------------- launcher ----------------

extern "C" void kernel_launch(void* const* d_in, const int* in_sizes, int n_in,
                              void* d_out, int out_size, void* d_ws, size_t ws_size,
                              hipStream_t stream) {
    const float* x   = (const float*)d_in[0];
    const int*   ei  = (const int*)d_in[1];
    const float* w1  = (const float*)d_in[3];
    const float* lw1 = (const float*)d_in[4];
    const float* lb1 = (const float*)d_in[5];
    const float* w2  = (const float*)d_in[6];
    const float* lw2 = (const float*)d_in[7];
    const float* lb2 = (const float*)d_in[8];
    const float* w3  = (const float*)d_in[9];
    const float* lw3 = (const float*)d_in[10];
    const float* lb3 = (const float*)d_in[11];
    float* out = (float*)d_out;

    char* ws = (char*)d_ws;
    size_t off = 0;
    auto alloc = [&](size_t bytes) -> void* {
        void* p = ws + off;
        off += (bytes + 255) & ~(size_t)255;
        return p;
    };
    int*   out_cnt     = (int*)alloc((size_t)NNODES * 4);
    int*   in_cnt      = (int*)alloc((size_t)NNODES * 4);
    int*   offsets     = (int*)alloc((size_t)(NNODES + 1) * 4);
    int*   cursor      = (int*)alloc((size_t)NNODES * 4);
    int*   src_sorted  = (int*)alloc((size_t)NEDGES * 4);
    float* norm_sorted = (float*)alloc((size_t)NEDGES * 4);
    bf16*  wts         = (bf16*)alloc((size_t)327680 * 2);
    bf16*  xw          = (bf16*)alloc((size_t)NNODES * 256 * 2);
    float* agg         = (float*)alloc((size_t)NNODES * 256 * 4);
    bf16*  h1          = (bf16*)alloc((size_t)NNODES * 256 * 2);
    bf16*  h2          = (bf16*)alloc((size_t)NNODES * 256 * 2);
    // total ws usage ~136 MB

    hipMemsetAsync(out_cnt, 0, (size_t)NNODES * 4, stream);
    hipMemsetAsync(in_cnt, 0, (size_t)NNODES * 4, stream);

    // weights -> bf16
    bf16* wb1  = wts;
    bf16* wlb1 = wts + 65536;
    bf16* wb2  = wts + 131072;
    bf16* wlb2 = wts + 196608;
    bf16* wb3  = wts + 262144;
    bf16* wlb3 = wts + 294912;
    k_f2b<<<256, 256, 0, stream>>>(w1, wb1, 65536);
    k_f2b<<<256, 256, 0, stream>>>(lw1, wlb1, 65536);
    k_f2b<<<256, 256, 0, stream>>>(w2, wb2, 65536);
    k_f2b<<<256, 256, 0, stream>>>(lw2, wlb2, 65536);
    k_f2b<<<128, 256, 0, stream>>>(w3, wb3, 32768);
    k_f2b<<<128, 256, 0, stream>>>(lw3, wlb3, 32768);

    // graph preprocessing: degrees -> CSR by destination + per-edge norm
    int eblocks = (NEDGES + 255) / 256;
    k_degree<<<eblocks, 256, 0, stream>>>(ei, out_cnt, in_cnt);
    k_scan<<<1, 1024, 0, stream>>>(in_cnt, offsets, cursor);
    k_scatter<<<eblocks, 256, 0, stream>>>(ei, out_cnt, in_cnt, cursor, src_sorted, norm_sorted);

    dim3 g256((NNODES + 63) / 64, 4);
    dim3 g128((NNODES + 63) / 64, 2);
    int ablocks = (NNODES + 3) / 4;

    // layer 1 (A = x fp32)
    k_gemm<256, 0, false><<<g256, 256, 0, stream>>>(x, wb1, nullptr, nullptr, xw);
    k_aggregate<256><<<ablocks, 256, 0, stream>>>(xw, offsets, src_sorted, norm_sorted, agg);
    k_gemm<256, 1, false><<<g256, 256, 0, stream>>>(x, wlb1, agg, lb1, h1);
    // layer 2
    k_gemm<256, 0, true><<<g256, 256, 0, stream>>>(h1, wb2, nullptr, nullptr, xw);
    k_aggregate<256><<<ablocks, 256, 0, stream>>>(xw, offsets, src_sorted, norm_sorted, agg);
    k_gemm<256, 1, true><<<g256, 256, 0, stream>>>(h1, wlb2, agg, lb2, h2);
    // layer 3 (C = 128, sigmoid -> fp32 out)
    k_gemm<128, 0, true><<<g128, 256, 0, stream>>>(h2, wb3, nullptr, nullptr, xw);
    k_aggregate<128><<<ablocks, 256, 0, stream>>>(xw, offsets, src_sorted, norm_sorted, agg);
    k_gemm<128, 2, true><<<g128, 256, 0, stream>>>(h2, wlb3, agg, lb3, out);
}

// Round 2
// 678.414 us; speedup vs baseline: 1.1300x; 1.1300x over previous
//
#include <hip/hip_runtime.h>
#include <hip/hip_bf16.h>
#include <math.h>

#define NNODES 50000
#define NEDGES 800000
#define SCAN_NB ((NNODES + 255) / 256)   // 196 blocks

typedef short s8v __attribute__((ext_vector_type(8)));
typedef float f4v __attribute__((ext_vector_type(4)));
using bf16 = __hip_bfloat16;

static __device__ __forceinline__ float bf2f(unsigned int u16) {
    union { unsigned int i; float f; } c; c.i = u16 << 16; return c.f;
}

// ---------------- small utility kernels ----------------

__global__ void k_f2b(const float* __restrict__ src, bf16* __restrict__ dst, int n) {
    int i = blockIdx.x * blockDim.x + threadIdx.x;
    if (i < n) dst[i] = __float2bfloat16(src[i]);
}

__global__ void k_degree(const int* __restrict__ ei, int* __restrict__ out_cnt, int* __restrict__ in_cnt) {
    int e = blockIdx.x * blockDim.x + threadIdx.x;
    if (e < NEDGES) {
        atomicAdd(&out_cnt[ei[e]], 1);
        atomicAdd(&in_cnt[ei[NEDGES + e]], 1);
    }
}

// ---------------- 3-phase parallel exclusive scan of in_cnt -> offsets[N+1] ----------------

__global__ void k_blocksum(const int* __restrict__ in_cnt, int* __restrict__ block_sums) {
    __shared__ int s[256];
    int b = blockIdx.x, t = threadIdx.x;
    int i = b * 256 + t;
    s[t] = (i < NNODES) ? in_cnt[i] : 0;
    __syncthreads();
    for (int off = 128; off > 0; off >>= 1) {
        if (t < off) s[t] += s[t + off];
        __syncthreads();
    }
    if (t == 0) block_sums[b] = s[0];
}

__global__ void k_scan_blocks(const int* __restrict__ block_sums, int* __restrict__ block_base, int nb) {
    __shared__ int s[256];
    int t = threadIdx.x;
    int v = (t < nb) ? block_sums[t] : 0;
    s[t] = v;
    __syncthreads();
    for (int off = 1; off < 256; off <<= 1) {
        int u = (t >= off) ? s[t - off] : 0;
        __syncthreads();
        s[t] += u;
        __syncthreads();
    }
    block_base[t] = s[t] - v;  // exclusive
}

__global__ void k_scan_final(const int* __restrict__ in_cnt, const int* __restrict__ block_base,
                             int* __restrict__ offsets, int* __restrict__ cursor) {
    __shared__ int s[256];
    int b = blockIdx.x, t = threadIdx.x;
    int i = b * 256 + t;
    int v = (i < NNODES) ? in_cnt[i] : 0;
    s[t] = v;
    __syncthreads();
    for (int off = 1; off < 256; off <<= 1) {
        int u = (t >= off) ? s[t - off] : 0;
        __syncthreads();
        s[t] += u;
        __syncthreads();
    }
    int excl = s[t] - v + block_base[b];
    if (i < NNODES) { offsets[i] = excl; cursor[i] = excl; }
    if (i == NNODES - 1) offsets[NNODES] = excl + v;
}

// counting-sort scatter: bucket edges by destination, precompute norm
__global__ void k_scatter(const int* __restrict__ ei, const int* __restrict__ out_cnt,
                          const int* __restrict__ in_cnt, int* __restrict__ cursor,
                          int* __restrict__ src_sorted, float* __restrict__ norm_sorted) {
    int e = blockIdx.x * blockDim.x + threadIdx.x;
    if (e < NEDGES) {
        int r = ei[e], c = ei[NEDGES + e];
        int p = atomicAdd(&cursor[c], 1);
        src_sorted[p] = r;
        norm_sorted[p] = rsqrtf((float)out_cnt[r] * (float)in_cnt[c]);
    }
}

// ---------------- aggregation: one wave per destination node ----------------

template<int D>
__global__ void k_aggregate(const bf16* __restrict__ xw, const int* __restrict__ offsets,
                            const int* __restrict__ src_sorted, const float* __restrict__ norm_sorted,
                            float* __restrict__ agg) {
    const int VPL = D / 64; // floats per lane: 4 (D=256) or 2 (D=128)
    int lane = threadIdx.x & 63;
    int v = blockIdx.x * (blockDim.x >> 6) + (threadIdx.x >> 6);
    if (v >= NNODES) return;
    float acc[VPL];
#pragma unroll
    for (int c = 0; c < VPL; ++c) acc[c] = 0.f;
    int beg = offsets[v], end = offsets[v + 1];
    for (int j = beg; j < end; ++j) {
        int s = src_sorted[j];
        float w = norm_sorted[j];
        const unsigned short* p = (const unsigned short*)(xw + (size_t)s * D) + lane * VPL;
        if (VPL == 4) {
            uint2 q = *(const uint2*)p;
            acc[0] += w * bf2f(q.x & 0xffffu);
            acc[1] += w * bf2f(q.x >> 16);
            acc[2] += w * bf2f(q.y & 0xffffu);
            acc[3] += w * bf2f(q.y >> 16);
        } else {
            unsigned int q = *(const unsigned int*)p;
            acc[0] += w * bf2f(q & 0xffffu);
            acc[1] += w * bf2f(q >> 16);
        }
    }
    float* o = agg + (size_t)v * D + lane * VPL;
#pragma unroll
    for (int c = 0; c < VPL; ++c) o[c] = acc[c];
}

// ---------------- MFMA GEMM: [N,256] @ [256,C], 64x64 tile, 4 waves ----------------
// EPI: 0 -> store bf16 (xw); 1 -> +agg+bias, relu -> bf16; 2 -> +agg+bias, sigmoid -> float
template<int C, int EPI, bool A_BF16>
__global__ __launch_bounds__(256) void k_gemm(const void* __restrict__ Aptr, const bf16* __restrict__ B,
                                              const float* __restrict__ agg, const float* __restrict__ bias,
                                              void* __restrict__ Out) {
    __shared__ bf16 As[64][40];   // rows x k (pad 32->40 to spread banks)
    __shared__ bf16 Bs[64][40];   // Bs[n][k] (transposed at staging)
    const int R = NNODES;
    int t = threadIdx.x;
    int wave = t >> 6, lane = t & 63;
    int r0 = blockIdx.x * 64;
    int n0 = blockIdx.y * 64;

    f4v acc[4];
#pragma unroll
    for (int i = 0; i < 4; ++i) acc[i] = (f4v){0.f, 0.f, 0.f, 0.f};

    int arow = t >> 2, aseg = t & 3;  // 64 rows x 4 segments of 8 bf16
    int bn = t & 63, bkseg = t >> 6;  // 64 cols x 4 ksegs of 8

    for (int k0 = 0; k0 < 256; k0 += 32) {
        { // stage A tile (convert fp32->bf16 on the fly for layer-1 input)
            union { bf16 h[8]; uint4 v; } u;
            int gr = r0 + arow;
            if (gr < R) {
                if (A_BF16) {
                    const bf16* Ab = (const bf16*)Aptr;
                    u.v = *(const uint4*)(Ab + (size_t)gr * 256 + k0 + aseg * 8);
                } else {
                    const float* Af = (const float*)Aptr;
                    const float4* p = (const float4*)(Af + (size_t)gr * 256 + k0 + aseg * 8);
                    float4 f0 = p[0], f1 = p[1];
                    u.h[0] = __float2bfloat16(f0.x); u.h[1] = __float2bfloat16(f0.y);
                    u.h[2] = __float2bfloat16(f0.z); u.h[3] = __float2bfloat16(f0.w);
                    u.h[4] = __float2bfloat16(f1.x); u.h[5] = __float2bfloat16(f1.y);
                    u.h[6] = __float2bfloat16(f1.z); u.h[7] = __float2bfloat16(f1.w);
                }
            } else {
                u.v = (uint4){0, 0, 0, 0};
            }
            *(uint4*)&As[arow][aseg * 8] = u.v;
        }
        { // stage B tile transposed: Bs[n][k]; global reads coalesced across threads per j
            union { bf16 h[8]; uint4 v; } u;
#pragma unroll
            for (int j = 0; j < 8; ++j)
                u.h[j] = B[(size_t)(k0 + bkseg * 8 + j) * C + n0 + bn];
            *(uint4*)&Bs[bn][bkseg * 8] = u.v;
        }
        __syncthreads();
        int m = wave * 16 + (lane & 15);
        int kq = (lane >> 4) * 8;
        s8v a = *(const s8v*)&As[m][kq];
#pragma unroll
        for (int nt = 0; nt < 4; ++nt) {
            s8v b = *(const s8v*)&Bs[nt * 16 + (lane & 15)][kq];
            acc[nt] = __builtin_amdgcn_mfma_f32_16x16x32_bf16(a, b, acc[nt], 0, 0, 0);
        }
        __syncthreads();
    }
    // epilogue: C/D layout col=lane&15, row=(lane>>4)*4+reg  [m89/m91-verified]
#pragma unroll
    for (int nt = 0; nt < 4; ++nt) {
#pragma unroll
        for (int r = 0; r < 4; ++r) {
            int grow = r0 + wave * 16 + (lane >> 4) * 4 + r;
            int gcol = n0 + nt * 16 + (lane & 15);
            if (grow < R) {
                float v = acc[nt][r];
                if (EPI == 0) {
                    ((bf16*)Out)[(size_t)grow * C + gcol] = __float2bfloat16(v);
                } else {
                    v += agg[(size_t)grow * C + gcol] + bias[gcol];
                    if (EPI == 1) {
                        v = fmaxf(v, 0.f);
                        ((bf16*)Out)[(size_t)grow * C + gcol] = __float2bfloat16(v);
                    } else {
                        v = 1.f / (1.f + expf(-v));
                        ((float*)Out)[(size_t)grow * C + gcol] = v;
                    }
                }
            }
        }
    }
}

// ---------------- launcher ----------------

extern "C" void kernel_launch(void* const* d_in, const int* in_sizes, int n_in,
                              void* d_out, int out_size, void* d_ws, size_t ws_size,
                              hipStream_t stream) {
    const float* x   = (const float*)d_in[0];
    const int*   ei  = (const int*)d_in[1];
    const float* w1  = (const float*)d_in[3];
    const float* lw1 = (const float*)d_in[4];
    const float* lb1 = (const float*)d_in[5];
    const float* w2  = (const float*)d_in[6];
    const float* lw2 = (const float*)d_in[7];
    const float* lb2 = (const float*)d_in[8];
    const float* w3  = (const float*)d_in[9];
    const float* lw3 = (const float*)d_in[10];
    const float* lb3 = (const float*)d_in[11];
    float* out = (float*)d_out;

    char* ws = (char*)d_ws;
    size_t off = 0;
    auto alloc = [&](size_t bytes) -> void* {
        void* p = ws + off;
        off += (bytes + 255) & ~(size_t)255;
        return p;
    };
    int*   out_cnt     = (int*)alloc((size_t)NNODES * 4);
    int*   in_cnt      = (int*)alloc((size_t)NNODES * 4);
    int*   offsets     = (int*)alloc((size_t)(NNODES + 1) * 4);
    int*   cursor      = (int*)alloc((size_t)NNODES * 4);
    int*   block_sums  = (int*)alloc((size_t)256 * 4);
    int*   block_base  = (int*)alloc((size_t)256 * 4);
    int*   src_sorted  = (int*)alloc((size_t)NEDGES * 4);
    float* norm_sorted = (float*)alloc((size_t)NEDGES * 4);
    bf16*  wts         = (bf16*)alloc((size_t)327680 * 2);
    bf16*  xw          = (bf16*)alloc((size_t)NNODES * 256 * 2);
    float* agg         = (float*)alloc((size_t)NNODES * 256 * 4);
    bf16*  h1          = (bf16*)alloc((size_t)NNODES * 256 * 2);
    bf16*  h2          = (bf16*)alloc((size_t)NNODES * 256 * 2);
    // total ws usage ~136 MB

    hipMemsetAsync(out_cnt, 0, (size_t)NNODES * 4, stream);
    hipMemsetAsync(in_cnt, 0, (size_t)NNODES * 4, stream);

    // weights -> bf16
    bf16* wb1  = wts;
    bf16* wlb1 = wts + 65536;
    bf16* wb2  = wts + 131072;
    bf16* wlb2 = wts + 196608;
    bf16* wb3  = wts + 262144;
    bf16* wlb3 = wts + 294912;
    k_f2b<<<256, 256, 0, stream>>>(w1, wb1, 65536);
    k_f2b<<<256, 256, 0, stream>>>(lw1, wlb1, 65536);
    k_f2b<<<256, 256, 0, stream>>>(w2, wb2, 65536);
    k_f2b<<<256, 256, 0, stream>>>(lw2, wlb2, 65536);
    k_f2b<<<128, 256, 0, stream>>>(w3, wb3, 32768);
    k_f2b<<<128, 256, 0, stream>>>(lw3, wlb3, 32768);

    // graph preprocessing: degrees -> CSR by destination + per-edge norm
    int eblocks = (NEDGES + 255) / 256;
    k_degree<<<eblocks, 256, 0, stream>>>(ei, out_cnt, in_cnt);
    k_blocksum<<<SCAN_NB, 256, 0, stream>>>(in_cnt, block_sums);
    k_scan_blocks<<<1, 256, 0, stream>>>(block_sums, block_base, SCAN_NB);
    k_scan_final<<<SCAN_NB, 256, 0, stream>>>(in_cnt, block_base, offsets, cursor);
    k_scatter<<<eblocks, 256, 0, stream>>>(ei, out_cnt, in_cnt, cursor, src_sorted, norm_sorted);

    dim3 g256((NNODES + 63) / 64, 4);
    dim3 g128((NNODES + 63) / 64, 2);
    int ablocks = (NNODES + 3) / 4;

    // layer 1 (A = x fp32)
    k_gemm<256, 0, false><<<g256, 256, 0, stream>>>(x, wb1, nullptr, nullptr, xw);
    k_aggregate<256><<<ablocks, 256, 0, stream>>>(xw, offsets, src_sorted, norm_sorted, agg);
    k_gemm<256, 1, false><<<g256, 256, 0, stream>>>(x, wlb1, agg, lb1, h1);
    // layer 2
    k_gemm<256, 0, true><<<g256, 256, 0, stream>>>(h1, wb2, nullptr, nullptr, xw);
    k_aggregate<256><<<ablocks, 256, 0, stream>>>(xw, offsets, src_sorted, norm_sorted, agg);
    k_gemm<256, 1, true><<<g256, 256, 0, stream>>>(h1, wlb2, agg, lb2, h2);
    // layer 3 (C = 128, sigmoid -> fp32 out)
    k_gemm<128, 0, true><<<g128, 256, 0, stream>>>(h2, wb3, nullptr, nullptr, xw);
    k_aggregate<128><<<ablocks, 256, 0, stream>>>(xw, offsets, src_sorted, norm_sorted, agg);
    k_gemm<128, 2, true><<<g128, 256, 0, stream>>>(h2, wlb3, agg, lb3, out);
}

// Round 3
// 486.571 us; speedup vs baseline: 1.5756x; 1.3943x over previous
//
#include <hip/hip_runtime.h>
#include <hip/hip_bf16.h>
#include <math.h>

#define NNODES 50000
#define NEDGES 800000
#define SCAN_NB ((NNODES + 255) / 256)   // 196 blocks

typedef short s8v __attribute__((ext_vector_type(8)));
typedef float f4v __attribute__((ext_vector_type(4)));
using bf16 = __hip_bfloat16;

static __device__ __forceinline__ float bf2f(unsigned int u16) {
    union { unsigned int i; float f; } c; c.i = u16 << 16; return c.f;
}

// ---------------- weight prep: pack [W | LW] -> bf16 wcat[K][2C] ----------------

__global__ void k_packb(const float* __restrict__ W, const float* __restrict__ LW,
                        bf16* __restrict__ out, int K, int C) {
    int i = blockIdx.x * blockDim.x + threadIdx.x;
    int C2 = 2 * C;
    if (i >= K * C2) return;
    int k = i / C2, j = i % C2;
    float v = (j < C) ? W[k * C + j] : LW[k * C + (j - C)];
    out[i] = __float2bfloat16(v);
}

// ---------------- graph preprocessing ----------------

__global__ void k_degree(const int* __restrict__ ei, int* __restrict__ out_cnt, int* __restrict__ in_cnt) {
    int e = blockIdx.x * blockDim.x + threadIdx.x;
    if (e < NEDGES) {
        atomicAdd(&out_cnt[ei[e]], 1);
        atomicAdd(&in_cnt[ei[NEDGES + e]], 1);
    }
}

__global__ void k_blocksum(const int* __restrict__ in_cnt, int* __restrict__ block_sums) {
    __shared__ int s[256];
    int b = blockIdx.x, t = threadIdx.x;
    int i = b * 256 + t;
    s[t] = (i < NNODES) ? in_cnt[i] : 0;
    __syncthreads();
    for (int off = 128; off > 0; off >>= 1) {
        if (t < off) s[t] += s[t + off];
        __syncthreads();
    }
    if (t == 0) block_sums[b] = s[0];
}

__global__ void k_scan_blocks(const int* __restrict__ block_sums, int* __restrict__ block_base, int nb) {
    __shared__ int s[256];
    int t = threadIdx.x;
    int v = (t < nb) ? block_sums[t] : 0;
    s[t] = v;
    __syncthreads();
    for (int off = 1; off < 256; off <<= 1) {
        int u = (t >= off) ? s[t - off] : 0;
        __syncthreads();
        s[t] += u;
        __syncthreads();
    }
    block_base[t] = s[t] - v;  // exclusive
}

__global__ void k_scan_final(const int* __restrict__ in_cnt, const int* __restrict__ block_base,
                             int* __restrict__ offsets, int* __restrict__ cursor) {
    __shared__ int s[256];
    int b = blockIdx.x, t = threadIdx.x;
    int i = b * 256 + t;
    int v = (i < NNODES) ? in_cnt[i] : 0;
    s[t] = v;
    __syncthreads();
    for (int off = 1; off < 256; off <<= 1) {
        int u = (t >= off) ? s[t - off] : 0;
        __syncthreads();
        s[t] += u;
        __syncthreads();
    }
    int excl = s[t] - v + block_base[b];
    if (i < NNODES) { offsets[i] = excl; cursor[i] = excl; }
    if (i == NNODES - 1) offsets[NNODES] = excl + v;
}

// counting-sort scatter: bucket edges by destination; (src, norm) interleaved as int2
__global__ void k_scatter(const int* __restrict__ ei, const int* __restrict__ out_cnt,
                          const int* __restrict__ in_cnt, int* __restrict__ cursor,
                          int2* __restrict__ edge_sn) {
    int e = blockIdx.x * blockDim.x + threadIdx.x;
    if (e < NEDGES) {
        int r = ei[e], c = ei[NEDGES + e];
        int p = atomicAdd(&cursor[c], 1);
        float nrm = rsqrtf((float)out_cnt[r] * (float)in_cnt[c]);
        edge_sn[p] = make_int2(r, __float_as_int(nrm));
    }
}

// ---------------- fused aggregate + residual + bias + activation ----------------
// One wave per destination node. L = D/8 lanes cover one row (16 B/lane); G = 64/L
// edges in parallel per iteration, unrolled x2 (A/B) -> 2G independent gathers in flight.
// After cross-group shuffle reduce, lanes < L apply xlw + bias + act and store h.
// ACT: 1 = relu -> bf16, 2 = sigmoid -> fp32
template<int D, int C2, int ACT>
__global__ void k_agg_fused(const bf16* __restrict__ xwcat, const int* __restrict__ offsets,
                            const int2* __restrict__ edge_sn, const float* __restrict__ bias,
                            void* __restrict__ out) {
    const int L = D / 8;    // 32 (D=256) or 16 (D=128)
    const int G = 64 / L;   // 2 or 4
    int lane = threadIdx.x & 63;
    int v = blockIdx.x * (blockDim.x >> 6) + (threadIdx.x >> 6);
    if (v >= NNODES) return;
    int g = lane / L, sl = lane % L;

    float accA[8], accB[8];
#pragma unroll
    for (int c = 0; c < 8; ++c) { accA[c] = 0.f; accB[c] = 0.f; }

    int beg = offsets[v], end = offsets[v + 1];
    const ushort* base = (const ushort*)xwcat + sl * 8;
    for (int j = beg + g; j < end; j += 2 * G) {
        int2 e = edge_sn[j];
        float w = __int_as_float(e.y);
        uint4 q = *(const uint4*)(base + (size_t)e.x * C2);
        accA[0] += w * bf2f(q.x & 0xffffu); accA[1] += w * bf2f(q.x >> 16);
        accA[2] += w * bf2f(q.y & 0xffffu); accA[3] += w * bf2f(q.y >> 16);
        accA[4] += w * bf2f(q.z & 0xffffu); accA[5] += w * bf2f(q.z >> 16);
        accA[6] += w * bf2f(q.w & 0xffffu); accA[7] += w * bf2f(q.w >> 16);
        int jB = j + G;
        if (jB < end) {
            int2 e2 = edge_sn[jB];
            float w2 = __int_as_float(e2.y);
            uint4 p = *(const uint4*)(base + (size_t)e2.x * C2);
            accB[0] += w2 * bf2f(p.x & 0xffffu); accB[1] += w2 * bf2f(p.x >> 16);
            accB[2] += w2 * bf2f(p.y & 0xffffu); accB[3] += w2 * bf2f(p.y >> 16);
            accB[4] += w2 * bf2f(p.z & 0xffffu); accB[5] += w2 * bf2f(p.z >> 16);
            accB[6] += w2 * bf2f(p.w & 0xffffu); accB[7] += w2 * bf2f(p.w >> 16);
        }
    }
#pragma unroll
    for (int c = 0; c < 8; ++c) accA[c] += accB[c];
    // reduce across groups: lanes [0,L) end with full sums
#pragma unroll
    for (int d = 32; d >= L; d >>= 1) {
#pragma unroll
        for (int c = 0; c < 8; ++c) accA[c] += __shfl_down(accA[c], d, 64);
    }

    if (lane < L) {
        // residual linear path (xlw = cols [D, 2D) of xwcat row v) + bias
        const ushort* lwp = (const ushort*)xwcat + (size_t)v * C2 + D + sl * 8;
        uint4 ql = *(const uint4*)lwp;
        const float* bp = bias + sl * 8;
        float4 b0 = *(const float4*)bp, b1 = *(const float4*)(bp + 4);
        float h[8];
        h[0] = accA[0] + bf2f(ql.x & 0xffffu) + b0.x;
        h[1] = accA[1] + bf2f(ql.x >> 16)     + b0.y;
        h[2] = accA[2] + bf2f(ql.y & 0xffffu) + b0.z;
        h[3] = accA[3] + bf2f(ql.y >> 16)     + b0.w;
        h[4] = accA[4] + bf2f(ql.z & 0xffffu) + b1.x;
        h[5] = accA[5] + bf2f(ql.z >> 16)     + b1.y;
        h[6] = accA[6] + bf2f(ql.w & 0xffffu) + b1.z;
        h[7] = accA[7] + bf2f(ql.w >> 16)     + b1.w;
        if (ACT == 1) {
            union { bf16 hh[8]; uint4 u; } o;
#pragma unroll
            for (int c = 0; c < 8; ++c) o.hh[c] = __float2bfloat16(fmaxf(h[c], 0.f));
            *(uint4*)((ushort*)out + (size_t)v * D + sl * 8) = o.u;
        } else {
            float r[8];
#pragma unroll
            for (int c = 0; c < 8; ++c) r[c] = 1.f / (1.f + expf(-h[c]));
            float* op = (float*)out + (size_t)v * D + sl * 8;
            *(float4*)op = (float4){r[0], r[1], r[2], r[3]};
            *(float4*)(op + 4) = (float4){r[4], r[5], r[6], r[7]};
        }
    }
}

// ---------------- fused MFMA GEMM: A[N,256] @ Bcat[256,C2] -> bf16 xwcat ----------------
// 64 rows x 128 cols per block, 4 waves; each wave: 16 rows x 128 cols = 8 MFMA tiles.
template<int C2, bool A_BF16>
__global__ __launch_bounds__(256) void k_gemm_fused(const void* __restrict__ Aptr,
                                                    const bf16* __restrict__ B,
                                                    bf16* __restrict__ Out) {
    __shared__ bf16 As[64][40];    // 64 rows x 32 k (pad to 40)
    __shared__ bf16 Bs[128][40];   // 128 cols x 32 k (transposed at staging)
    const int R = NNODES;
    int t = threadIdx.x;
    int wave = t >> 6, lane = t & 63;
    int r0 = blockIdx.x * 64;
    int n0 = blockIdx.y * 128;

    f4v acc[8];
#pragma unroll
    for (int i = 0; i < 8; ++i) acc[i] = (f4v){0.f, 0.f, 0.f, 0.f};

    int arow = t >> 2, aseg = t & 3;   // A: 64 rows x 4 segs of 8
    int bn = t & 127, bhalf = t >> 7;  // B: 128 cols, 2 ksegs each

    for (int k0 = 0; k0 < 256; k0 += 32) {
        { // stage A (fp32->bf16 convert for layer 1)
            union { bf16 h[8]; uint4 v; } u;
            int gr = r0 + arow;
            if (gr < R) {
                if (A_BF16) {
                    const bf16* Ab = (const bf16*)Aptr;
                    u.v = *(const uint4*)(Ab + (size_t)gr * 256 + k0 + aseg * 8);
                } else {
                    const float* Af = (const float*)Aptr;
                    const float4* p = (const float4*)(Af + (size_t)gr * 256 + k0 + aseg * 8);
                    float4 f0 = p[0], f1 = p[1];
                    u.h[0] = __float2bfloat16(f0.x); u.h[1] = __float2bfloat16(f0.y);
                    u.h[2] = __float2bfloat16(f0.z); u.h[3] = __float2bfloat16(f0.w);
                    u.h[4] = __float2bfloat16(f1.x); u.h[5] = __float2bfloat16(f1.y);
                    u.h[6] = __float2bfloat16(f1.z); u.h[7] = __float2bfloat16(f1.w);
                }
            } else {
                u.v = (uint4){0, 0, 0, 0};
            }
            *(uint4*)&As[arow][aseg * 8] = u.v;
        }
        { // stage B transposed: Bs[n][k]; coalesced across bn for each (kseg, j)
#pragma unroll
            for (int s8 = 0; s8 < 2; ++s8) {
                int kseg = bhalf * 2 + s8;
                union { bf16 h[8]; uint4 v; } u;
#pragma unroll
                for (int j = 0; j < 8; ++j)
                    u.h[j] = B[(size_t)(k0 + kseg * 8 + j) * C2 + n0 + bn];
                *(uint4*)&Bs[bn][kseg * 8] = u.v;
            }
        }
        __syncthreads();
        int m = wave * 16 + (lane & 15);
        int kq = (lane >> 4) * 8;
        s8v a = *(const s8v*)&As[m][kq];
#pragma unroll
        for (int nt = 0; nt < 8; ++nt) {
            s8v b = *(const s8v*)&Bs[nt * 16 + (lane & 15)][kq];
            acc[nt] = __builtin_amdgcn_mfma_f32_16x16x32_bf16(a, b, acc[nt], 0, 0, 0);
        }
        __syncthreads();
    }
    // C/D layout: col=lane&15, row=(lane>>4)*4+reg
#pragma unroll
    for (int nt = 0; nt < 8; ++nt) {
#pragma unroll
        for (int r = 0; r < 4; ++r) {
            int grow = r0 + wave * 16 + (lane >> 4) * 4 + r;
            int gcol = n0 + nt * 16 + (lane & 15);
            if (grow < R)
                Out[(size_t)grow * C2 + gcol] = __float2bfloat16(acc[nt][r]);
        }
    }
}

// ---------------- launcher ----------------

extern "C" void kernel_launch(void* const* d_in, const int* in_sizes, int n_in,
                              void* d_out, int out_size, void* d_ws, size_t ws_size,
                              hipStream_t stream) {
    const float* x   = (const float*)d_in[0];
    const int*   ei  = (const int*)d_in[1];
    const float* w1  = (const float*)d_in[3];
    const float* lw1 = (const float*)d_in[4];
    const float* lb1 = (const float*)d_in[5];
    const float* w2  = (const float*)d_in[6];
    const float* lw2 = (const float*)d_in[7];
    const float* lb2 = (const float*)d_in[8];
    const float* w3  = (const float*)d_in[9];
    const float* lw3 = (const float*)d_in[10];
    const float* lb3 = (const float*)d_in[11];
    float* out = (float*)d_out;

    char* ws = (char*)d_ws;
    size_t off = 0;
    auto alloc = [&](size_t bytes) -> void* {
        void* p = ws + off;
        off += (bytes + 255) & ~(size_t)255;
        return p;
    };
    int*   out_cnt    = (int*)alloc((size_t)NNODES * 4);
    int*   in_cnt     = (int*)alloc((size_t)NNODES * 4);
    int*   offsets    = (int*)alloc((size_t)(NNODES + 1) * 4);
    int*   cursor     = (int*)alloc((size_t)NNODES * 4);
    int*   block_sums = (int*)alloc((size_t)256 * 4);
    int*   block_base = (int*)alloc((size_t)256 * 4);
    int2*  edge_sn    = (int2*)alloc((size_t)NEDGES * 8);
    bf16*  wcat1      = (bf16*)alloc((size_t)256 * 512 * 2);
    bf16*  wcat2      = (bf16*)alloc((size_t)256 * 512 * 2);
    bf16*  wcat3      = (bf16*)alloc((size_t)256 * 256 * 2);
    bf16*  xwcat      = (bf16*)alloc((size_t)NNODES * 512 * 2);
    bf16*  h1         = (bf16*)alloc((size_t)NNODES * 256 * 2);
    bf16*  h2         = (bf16*)alloc((size_t)NNODES * 256 * 2);
    // ~112 MB total

    hipMemsetAsync(out_cnt, 0, (size_t)NNODES * 4, stream);
    hipMemsetAsync(in_cnt, 0, (size_t)NNODES * 4, stream);

    // pack weights -> bf16 [W | LW]
    k_packb<<<512, 256, 0, stream>>>(w1, lw1, wcat1, 256, 256);
    k_packb<<<512, 256, 0, stream>>>(w2, lw2, wcat2, 256, 256);
    k_packb<<<256, 256, 0, stream>>>(w3, lw3, wcat3, 256, 128);

    // graph preprocessing: degrees -> CSR by destination + per-edge (src, norm)
    int eblocks = (NEDGES + 255) / 256;
    k_degree<<<eblocks, 256, 0, stream>>>(ei, out_cnt, in_cnt);
    k_blocksum<<<SCAN_NB, 256, 0, stream>>>(in_cnt, block_sums);
    k_scan_blocks<<<1, 256, 0, stream>>>(block_sums, block_base, SCAN_NB);
    k_scan_final<<<SCAN_NB, 256, 0, stream>>>(in_cnt, block_base, offsets, cursor);
    k_scatter<<<eblocks, 256, 0, stream>>>(ei, out_cnt, in_cnt, cursor, edge_sn);

    int gx = (NNODES + 63) / 64;  // 782
    int ablocks = NNODES / 4;     // 12500 (4 waves/block, 1 node/wave)

    // layer 1: x fp32 -> xwcat[N][512] -> h1 = relu(agg + xlw + b1)
    k_gemm_fused<512, false><<<dim3(gx, 4), 256, 0, stream>>>(x, wcat1, xwcat);
    k_agg_fused<256, 512, 1><<<ablocks, 256, 0, stream>>>(xwcat, offsets, edge_sn, lb1, h1);
    // layer 2
    k_gemm_fused<512, true><<<dim3(gx, 4), 256, 0, stream>>>(h1, wcat2, xwcat);
    k_agg_fused<256, 512, 1><<<ablocks, 256, 0, stream>>>(xwcat, offsets, edge_sn, lb2, h2);
    // layer 3: C2=256, sigmoid -> fp32 out
    k_gemm_fused<256, true><<<dim3(gx, 2), 256, 0, stream>>>(h2, wcat3, xwcat);
    k_agg_fused<128, 256, 2><<<ablocks, 256, 0, stream>>>(xwcat, offsets, edge_sn, lb3, out);
}

// Round 4
// 457.319 us; speedup vs baseline: 1.6763x; 1.0640x over previous
//
#include <hip/hip_runtime.h>
#include <hip/hip_bf16.h>
#include <math.h>

#define NNODES 50000
#define NEDGES 800000
#define HNB 128                 // histogram blocks per row
#define HBINS 50176             // 196*256, >= NNODES
#define SCAN_NB 196             // HBINS/256

typedef short s8v __attribute__((ext_vector_type(8)));
typedef float f4v __attribute__((ext_vector_type(4)));
using bf16 = __hip_bfloat16;

static __device__ __forceinline__ float bf2f(unsigned int u16) {
    union { unsigned int i; float f; } c; c.i = u16 << 16; return c.f;
}

// ---------------- weight prep: pack [W | LW] -> bf16 wcat[K][2C] ----------------

__global__ void k_packb(const float* __restrict__ W, const float* __restrict__ LW,
                        bf16* __restrict__ out, int K, int C) {
    int i = blockIdx.x * blockDim.x + threadIdx.x;
    int C2 = 2 * C;
    if (i >= K * C2) return;
    int k = i / C2, j = i % C2;
    float v = (j < C) ? W[k * C + j] : LW[k * C + (j - C)];
    out[i] = __float2bfloat16(v);
}

// ---------------- degree histograms via LDS (no global atomics) ----------------
// grid (HNB, 2): y=0 -> out-degree (ei row 0), y=1 -> in-degree (ei row 1).
// Packed 2x16-bit LDS atomics; per-chunk count <= 6250 < 65536, no overflow.

__global__ __launch_bounds__(256) void k_hist(const int* __restrict__ ei, ushort* __restrict__ partials) {
    __shared__ unsigned int h32[HBINS / 2];   // 100352 B LDS
    int b = blockIdx.x, row = blockIdx.y, t = threadIdx.x;
    for (int i = t; i < HBINS / 2; i += 256) h32[i] = 0;
    __syncthreads();
    const int chunk = NEDGES / HNB;  // 6250
    int beg = b * chunk, end = beg + chunk;
    const int* p = ei + (size_t)row * NEDGES;
    for (int e = beg + t; e < end; e += 256) {
        int id = p[e];
        atomicAdd(&h32[id >> 1], 1u << (16 * (id & 1)));
    }
    __syncthreads();
    unsigned int* o32 = (unsigned int*)(partials + ((size_t)row * HNB + b) * HBINS);
    for (int i = t; i < HBINS / 2; i += 256) o32[i] = h32[i];
}

// reduce partials: y=0 -> rsqrt_out table; y=1 -> in_cnt + per-256-node block_sums
__global__ __launch_bounds__(256) void k_hist_reduce(const ushort* __restrict__ partials,
                                                     float* __restrict__ rsqrt_out,
                                                     int* __restrict__ in_cnt,
                                                     int* __restrict__ block_sums) {
    __shared__ int sm[256];
    int row = blockIdx.y;
    int i = blockIdx.x * 256 + threadIdx.x;
    const ushort* p = partials + (size_t)row * HNB * HBINS + i;
    int s = 0;
#pragma unroll 4
    for (int b = 0; b < HNB; ++b) s += p[(size_t)b * HBINS];
    if (row == 0) {
        if (i < NNODES) rsqrt_out[i] = rsqrtf((float)s);
    } else {
        if (i < NNODES) in_cnt[i] = s;
        sm[threadIdx.x] = s;   // s==0 automatically for i>=NNODES (ids < NNODES)
        __syncthreads();
        for (int off = 128; off > 0; off >>= 1) {
            if (threadIdx.x < off) sm[threadIdx.x] += sm[threadIdx.x + off];
            __syncthreads();
        }
        if (threadIdx.x == 0) block_sums[blockIdx.x] = sm[0];
    }
}

// ---------------- scan ----------------

__global__ void k_scan_blocks(const int* __restrict__ block_sums, int* __restrict__ block_base, int nb) {
    __shared__ int s[256];
    int t = threadIdx.x;
    int v = (t < nb) ? block_sums[t] : 0;
    s[t] = v;
    __syncthreads();
    for (int off = 1; off < 256; off <<= 1) {
        int u = (t >= off) ? s[t - off] : 0;
        __syncthreads();
        s[t] += u;
        __syncthreads();
    }
    block_base[t] = s[t] - v;  // exclusive
}

__global__ void k_scan_final(const int* __restrict__ in_cnt, const int* __restrict__ block_base,
                             int* __restrict__ offsets, int* __restrict__ cursor) {
    __shared__ int s[256];
    int b = blockIdx.x, t = threadIdx.x;
    int i = b * 256 + t;
    int v = (i < NNODES) ? in_cnt[i] : 0;
    s[t] = v;
    __syncthreads();
    for (int off = 1; off < 256; off <<= 1) {
        int u = (t >= off) ? s[t - off] : 0;
        __syncthreads();
        s[t] += u;
        __syncthreads();
    }
    int excl = s[t] - v + block_base[b];
    if (i < NNODES) { offsets[i] = excl; cursor[i] = excl; }
    if (i == NNODES - 1) offsets[NNODES] = excl + v;
}

// counting-sort scatter: src id only (norm factored out of edge record)
__global__ void k_scatter(const int* __restrict__ ei, int* __restrict__ cursor,
                          int* __restrict__ src_sorted) {
    int e = blockIdx.x * blockDim.x + threadIdx.x;
    if (e < NEDGES) {
        int r = ei[e], c = ei[NEDGES + e];
        int p = atomicAdd(&cursor[c], 1);
        src_sorted[p] = r;
    }
}

// ---------------- fused aggregate + residual + bias + activation ----------------
// agg[v] = rsqrt(in_deg[v]) * sum_e rsqrt_out[src_e] * xw[src_e]
// One wave per node; L = D/8 lanes per row (16 B/lane), G = 64/L edges in
// parallel, unrolled x2. ACT: 1 = relu -> bf16, 2 = sigmoid -> fp32.
template<int D, int C2, int ACT>
__global__ void k_agg_fused(const bf16* __restrict__ xwcat, const int* __restrict__ offsets,
                            const int* __restrict__ src_sorted, const float* __restrict__ rsqrt_out,
                            const float* __restrict__ bias, void* __restrict__ out) {
    const int L = D / 8;    // 32 (D=256) or 16 (D=128)
    const int G = 64 / L;   // 2 or 4
    int lane = threadIdx.x & 63;
    int v = blockIdx.x * (blockDim.x >> 6) + (threadIdx.x >> 6);
    if (v >= NNODES) return;
    int g = lane / L, sl = lane % L;

    float accA[8], accB[8];
#pragma unroll
    for (int c = 0; c < 8; ++c) { accA[c] = 0.f; accB[c] = 0.f; }

    int beg = offsets[v], end = offsets[v + 1];
    const ushort* base = (const ushort*)xwcat + sl * 8;
    for (int j = beg + g; j < end; j += 2 * G) {
        int s = src_sorted[j];
        float w = rsqrt_out[s];
        uint4 q = *(const uint4*)(base + (size_t)s * C2);
        accA[0] += w * bf2f(q.x & 0xffffu); accA[1] += w * bf2f(q.x >> 16);
        accA[2] += w * bf2f(q.y & 0xffffu); accA[3] += w * bf2f(q.y >> 16);
        accA[4] += w * bf2f(q.z & 0xffffu); accA[5] += w * bf2f(q.z >> 16);
        accA[6] += w * bf2f(q.w & 0xffffu); accA[7] += w * bf2f(q.w >> 16);
        int jB = j + G;
        if (jB < end) {
            int s2 = src_sorted[jB];
            float w2 = rsqrt_out[s2];
            uint4 p = *(const uint4*)(base + (size_t)s2 * C2);
            accB[0] += w2 * bf2f(p.x & 0xffffu); accB[1] += w2 * bf2f(p.x >> 16);
            accB[2] += w2 * bf2f(p.y & 0xffffu); accB[3] += w2 * bf2f(p.y >> 16);
            accB[4] += w2 * bf2f(p.z & 0xffffu); accB[5] += w2 * bf2f(p.z >> 16);
            accB[6] += w2 * bf2f(p.w & 0xffffu); accB[7] += w2 * bf2f(p.w >> 16);
        }
    }
#pragma unroll
    for (int c = 0; c < 8; ++c) accA[c] += accB[c];
    // reduce across groups: lanes [0,L) end with full sums
#pragma unroll
    for (int d = 32; d >= L; d >>= 1) {
#pragma unroll
        for (int c = 0; c < 8; ++c) accA[c] += __shfl_down(accA[c], d, 64);
    }

    if (lane < L) {
        float sc = (end > beg) ? rsqrtf((float)(end - beg)) : 0.f;
        const ushort* lwp = (const ushort*)xwcat + (size_t)v * C2 + D + sl * 8;
        uint4 ql = *(const uint4*)lwp;
        const float* bp = bias + sl * 8;
        float4 b0 = *(const float4*)bp, b1 = *(const float4*)(bp + 4);
        float h[8];
        h[0] = accA[0] * sc + bf2f(ql.x & 0xffffu) + b0.x;
        h[1] = accA[1] * sc + bf2f(ql.x >> 16)     + b0.y;
        h[2] = accA[2] * sc + bf2f(ql.y & 0xffffu) + b0.z;
        h[3] = accA[3] * sc + bf2f(ql.y >> 16)     + b0.w;
        h[4] = accA[4] * sc + bf2f(ql.z & 0xffffu) + b1.x;
        h[5] = accA[5] * sc + bf2f(ql.z >> 16)     + b1.y;
        h[6] = accA[6] * sc + bf2f(ql.w & 0xffffu) + b1.z;
        h[7] = accA[7] * sc + bf2f(ql.w >> 16)     + b1.w;
        if (ACT == 1) {
            union { bf16 hh[8]; uint4 u; } o;
#pragma unroll
            for (int c = 0; c < 8; ++c) o.hh[c] = __float2bfloat16(fmaxf(h[c], 0.f));
            *(uint4*)((ushort*)out + (size_t)v * D + sl * 8) = o.u;
        } else {
            float r[8];
#pragma unroll
            for (int c = 0; c < 8; ++c) r[c] = 1.f / (1.f + expf(-h[c]));
            float* op = (float*)out + (size_t)v * D + sl * 8;
            *(float4*)op = (float4){r[0], r[1], r[2], r[3]};
            *(float4*)(op + 4) = (float4){r[4], r[5], r[6], r[7]};
        }
    }
}

// ---------------- fused MFMA GEMM: A[N,256] @ Bcat[256,C2] -> bf16 xwcat ----------------
template<int C2, bool A_BF16>
__global__ __launch_bounds__(256) void k_gemm_fused(const void* __restrict__ Aptr,
                                                    const bf16* __restrict__ B,
                                                    bf16* __restrict__ Out) {
    __shared__ bf16 As[64][40];
    __shared__ bf16 Bs[128][40];
    const int R = NNODES;
    int t = threadIdx.x;
    int wave = t >> 6, lane = t & 63;
    int r0 = blockIdx.x * 64;
    int n0 = blockIdx.y * 128;

    f4v acc[8];
#pragma unroll
    for (int i = 0; i < 8; ++i) acc[i] = (f4v){0.f, 0.f, 0.f, 0.f};

    int arow = t >> 2, aseg = t & 3;
    int bn = t & 127, bhalf = t >> 7;

    for (int k0 = 0; k0 < 256; k0 += 32) {
        {
            union { bf16 h[8]; uint4 v; } u;
            int gr = r0 + arow;
            if (gr < R) {
                if (A_BF16) {
                    const bf16* Ab = (const bf16*)Aptr;
                    u.v = *(const uint4*)(Ab + (size_t)gr * 256 + k0 + aseg * 8);
                } else {
                    const float* Af = (const float*)Aptr;
                    const float4* p = (const float4*)(Af + (size_t)gr * 256 + k0 + aseg * 8);
                    float4 f0 = p[0], f1 = p[1];
                    u.h[0] = __float2bfloat16(f0.x); u.h[1] = __float2bfloat16(f0.y);
                    u.h[2] = __float2bfloat16(f0.z); u.h[3] = __float2bfloat16(f0.w);
                    u.h[4] = __float2bfloat16(f1.x); u.h[5] = __float2bfloat16(f1.y);
                    u.h[6] = __float2bfloat16(f1.z); u.h[7] = __float2bfloat16(f1.w);
                }
            } else {
                u.v = (uint4){0, 0, 0, 0};
            }
            *(uint4*)&As[arow][aseg * 8] = u.v;
        }
        {
#pragma unroll
            for (int s8 = 0; s8 < 2; ++s8) {
                int kseg = bhalf * 2 + s8;
                union { bf16 h[8]; uint4 v; } u;
#pragma unroll
                for (int j = 0; j < 8; ++j)
                    u.h[j] = B[(size_t)(k0 + kseg * 8 + j) * C2 + n0 + bn];
                *(uint4*)&Bs[bn][kseg * 8] = u.v;
            }
        }
        __syncthreads();
        int m = wave * 16 + (lane & 15);
        int kq = (lane >> 4) * 8;
        s8v a = *(const s8v*)&As[m][kq];
#pragma unroll
        for (int nt = 0; nt < 8; ++nt) {
            s8v b = *(const s8v*)&Bs[nt * 16 + (lane & 15)][kq];
            acc[nt] = __builtin_amdgcn_mfma_f32_16x16x32_bf16(a, b, acc[nt], 0, 0, 0);
        }
        __syncthreads();
    }
#pragma unroll
    for (int nt = 0; nt < 8; ++nt) {
#pragma unroll
        for (int r = 0; r < 4; ++r) {
            int grow = r0 + wave * 16 + (lane >> 4) * 4 + r;
            int gcol = n0 + nt * 16 + (lane & 15);
            if (grow < R)
                Out[(size_t)grow * C2 + gcol] = __float2bfloat16(acc[nt][r]);
        }
    }
}

// ---------------- launcher ----------------

extern "C" void kernel_launch(void* const* d_in, const int* in_sizes, int n_in,
                              void* d_out, int out_size, void* d_ws, size_t ws_size,
                              hipStream_t stream) {
    const float* x   = (const float*)d_in[0];
    const int*   ei  = (const int*)d_in[1];
    const float* w1  = (const float*)d_in[3];
    const float* lw1 = (const float*)d_in[4];
    const float* lb1 = (const float*)d_in[5];
    const float* w2  = (const float*)d_in[6];
    const float* lw2 = (const float*)d_in[7];
    const float* lb2 = (const float*)d_in[8];
    const float* w3  = (const float*)d_in[9];
    const float* lw3 = (const float*)d_in[10];
    const float* lb3 = (const float*)d_in[11];
    float* out = (float*)d_out;

    char* ws = (char*)d_ws;
    size_t off = 0;
    auto alloc = [&](size_t bytes) -> void* {
        void* p = ws + off;
        off += (bytes + 255) & ~(size_t)255;
        return p;
    };
    int*    in_cnt     = (int*)alloc((size_t)HBINS * 4);
    float*  rsqrt_out  = (float*)alloc((size_t)HBINS * 4);
    int*    offsets    = (int*)alloc((size_t)(NNODES + 1) * 4);
    int*    cursor     = (int*)alloc((size_t)NNODES * 4);
    int*    block_sums = (int*)alloc((size_t)256 * 4);
    int*    block_base = (int*)alloc((size_t)256 * 4);
    ushort* partials   = (ushort*)alloc((size_t)2 * HNB * HBINS * 2);   // 25.7 MB
    int*    src_sorted = (int*)alloc((size_t)NEDGES * 4);
    bf16*   wcat1      = (bf16*)alloc((size_t)256 * 512 * 2);
    bf16*   wcat2      = (bf16*)alloc((size_t)256 * 512 * 2);
    bf16*   wcat3      = (bf16*)alloc((size_t)256 * 256 * 2);
    bf16*   xwcat      = (bf16*)alloc((size_t)NNODES * 512 * 2);
    bf16*   h1         = (bf16*)alloc((size_t)NNODES * 256 * 2);
    bf16*   h2         = (bf16*)alloc((size_t)NNODES * 256 * 2);
    // ~134 MB total

    // pack weights -> bf16 [W | LW]
    k_packb<<<512, 256, 0, stream>>>(w1, lw1, wcat1, 256, 256);
    k_packb<<<512, 256, 0, stream>>>(w2, lw2, wcat2, 256, 256);
    k_packb<<<256, 256, 0, stream>>>(w3, lw3, wcat3, 256, 128);

    // graph preprocessing: LDS histograms -> reduce -> scan -> scatter
    k_hist<<<dim3(HNB, 2), 256, 0, stream>>>(ei, partials);
    k_hist_reduce<<<dim3(SCAN_NB, 2), 256, 0, stream>>>(partials, rsqrt_out, in_cnt, block_sums);
    k_scan_blocks<<<1, 256, 0, stream>>>(block_sums, block_base, SCAN_NB);
    k_scan_final<<<SCAN_NB, 256, 0, stream>>>(in_cnt, block_base, offsets, cursor);
    int eblocks = (NEDGES + 255) / 256;
    k_scatter<<<eblocks, 256, 0, stream>>>(ei, cursor, src_sorted);

    int gx = (NNODES + 63) / 64;  // 782
    int ablocks = NNODES / 4;     // 12500

    // layer 1
    k_gemm_fused<512, false><<<dim3(gx, 4), 256, 0, stream>>>(x, wcat1, xwcat);
    k_agg_fused<256, 512, 1><<<ablocks, 256, 0, stream>>>(xwcat, offsets, src_sorted, rsqrt_out, lb1, h1);
    // layer 2
    k_gemm_fused<512, true><<<dim3(gx, 4), 256, 0, stream>>>(h1, wcat2, xwcat);
    k_agg_fused<256, 512, 1><<<ablocks, 256, 0, stream>>>(xwcat, offsets, src_sorted, rsqrt_out, lb2, h2);
    // layer 3
    k_gemm_fused<256, true><<<dim3(gx, 2), 256, 0, stream>>>(h2, wcat3, xwcat);
    k_agg_fused<128, 256, 2><<<ablocks, 256, 0, stream>>>(xwcat, offsets, src_sorted, rsqrt_out, lb3, out);
}

// Round 5
// 440.651 us; speedup vs baseline: 1.7397x; 1.0378x over previous
//
#include <hip/hip_runtime.h>
#include <hip/hip_bf16.h>
#include <math.h>

#define NNODES 50000
#define NEDGES 800000
#define HNB 128                 // histogram blocks per row
#define HBINS 50176             // 196*256, >= NNODES
#define SCAN_NB 196             // HBINS/256

typedef short s8v __attribute__((ext_vector_type(8)));
typedef float f4v __attribute__((ext_vector_type(4)));
using bf16 = __hip_bfloat16;

static __device__ __forceinline__ float bflo(unsigned int x) {
    union { unsigned int i; float f; } c; c.i = x << 16; return c.f;
}
static __device__ __forceinline__ float bfhi(unsigned int x) {
    union { unsigned int i; float f; } c; c.i = x & 0xffff0000u; return c.f;
}

// ---------------- weight prep: pack [W | LW] -> bf16 wcat[K][2C] ----------------

__global__ void k_packb(const float* __restrict__ W, const float* __restrict__ LW,
                        bf16* __restrict__ out, int K, int C) {
    int i = blockIdx.x * blockDim.x + threadIdx.x;
    int C2 = 2 * C;
    if (i >= K * C2) return;
    int k = i / C2, j = i % C2;
    float v = (j < C) ? W[k * C + j] : LW[k * C + (j - C)];
    out[i] = __float2bfloat16(v);
}

// ---------------- degree histograms via LDS (no global atomics) ----------------

__global__ __launch_bounds__(256) void k_hist(const int* __restrict__ ei, ushort* __restrict__ partials) {
    __shared__ unsigned int h32[HBINS / 2];   // 100352 B LDS
    int b = blockIdx.x, row = blockIdx.y, t = threadIdx.x;
    for (int i = t; i < HBINS / 2; i += 256) h32[i] = 0;
    __syncthreads();
    const int chunk = NEDGES / HNB;  // 6250
    int beg = b * chunk, end = beg + chunk;
    const int* p = ei + (size_t)row * NEDGES;
    for (int e = beg + t; e < end; e += 256) {
        int id = p[e];
        atomicAdd(&h32[id >> 1], 1u << (16 * (id & 1)));
    }
    __syncthreads();
    unsigned int* o32 = (unsigned int*)(partials + ((size_t)row * HNB + b) * HBINS);
    for (int i = t; i < HBINS / 2; i += 256) o32[i] = h32[i];
}

// reduce partials: y=0 -> rsqrt_out table; y=1 -> in_cnt + per-256-node block_sums
__global__ __launch_bounds__(256) void k_hist_reduce(const ushort* __restrict__ partials,
                                                     float* __restrict__ rsqrt_out,
                                                     int* __restrict__ in_cnt,
                                                     int* __restrict__ block_sums) {
    __shared__ int sm[256];
    int row = blockIdx.y;
    int i = blockIdx.x * 256 + threadIdx.x;
    const ushort* p = partials + (size_t)row * HNB * HBINS + i;
    int s = 0;
#pragma unroll 4
    for (int b = 0; b < HNB; ++b) s += p[(size_t)b * HBINS];
    if (row == 0) {
        if (i < NNODES) rsqrt_out[i] = rsqrtf((float)s);
    } else {
        if (i < NNODES) in_cnt[i] = s;
        sm[threadIdx.x] = s;
        __syncthreads();
        for (int off = 128; off > 0; off >>= 1) {
            if (threadIdx.x < off) sm[threadIdx.x] += sm[threadIdx.x + off];
            __syncthreads();
        }
        if (threadIdx.x == 0) block_sums[blockIdx.x] = sm[0];
    }
}

// ---------------- scan ----------------

__global__ void k_scan_blocks(const int* __restrict__ block_sums, int* __restrict__ block_base, int nb) {
    __shared__ int s[256];
    int t = threadIdx.x;
    int v = (t < nb) ? block_sums[t] : 0;
    s[t] = v;
    __syncthreads();
    for (int off = 1; off < 256; off <<= 1) {
        int u = (t >= off) ? s[t - off] : 0;
        __syncthreads();
        s[t] += u;
        __syncthreads();
    }
    block_base[t] = s[t] - v;  // exclusive
}

__global__ void k_scan_final(const int* __restrict__ in_cnt, const int* __restrict__ block_base,
                             int* __restrict__ offsets, int* __restrict__ cursor) {
    __shared__ int s[256];
    int b = blockIdx.x, t = threadIdx.x;
    int i = b * 256 + t;
    int v = (i < NNODES) ? in_cnt[i] : 0;
    s[t] = v;
    __syncthreads();
    for (int off = 1; off < 256; off <<= 1) {
        int u = (t >= off) ? s[t - off] : 0;
        __syncthreads();
        s[t] += u;
        __syncthreads();
    }
    int excl = s[t] - v + block_base[b];
    if (i < NNODES) { offsets[i] = excl; cursor[i] = excl; }
    if (i == NNODES - 1) offsets[NNODES] = excl + v;
}

// counting-sort scatter: src id only
__global__ void k_scatter(const int* __restrict__ ei, int* __restrict__ cursor,
                          int* __restrict__ src_sorted) {
    int e = blockIdx.x * blockDim.x + threadIdx.x;
    if (e < NEDGES) {
        int r = ei[e], c = ei[NEDGES + e];
        int p = atomicAdd(&cursor[c], 1);
        src_sorted[p] = r;
    }
}

// ---------------- fused aggregate + residual + bias + activation ----------------
// One 64-thread block per node. Bucket edge ids + norms preloaded into registers
// (one coalesced load + one 4B gather), broadcast to groups via __shfl so the
// row-gather chain has no serial global dependency. L = D/8 lanes per row
// (16 B/lane), G = 64/L groups, unroll U=4 -> G*U row-gathers in flight.
// ACT: 1 = relu -> bf16, 2 = sigmoid -> fp32.
template<int D, int C2, int ACT>
__global__ __launch_bounds__(64) void k_agg_fused(const bf16* __restrict__ xwcat,
                                                  const int* __restrict__ offsets,
                                                  const int* __restrict__ src_sorted,
                                                  const float* __restrict__ rsqrt_out,
                                                  const float* __restrict__ bias,
                                                  void* __restrict__ out) {
    const int L = D / 8;    // 32 (D=256) or 16 (D=128)
    const int G = 64 / L;   // 2 or 4
    const int U = 4;
    int lane = threadIdx.x;
    int v = blockIdx.x;
    int g = lane / L, sl = lane % L;

    int beg = offsets[v], end = offsets[v + 1];
    int deg = end - beg;
    int dcap = min(deg, 64);

    // preload bucket (lanes >= dcap hold id=0, w=0 -> harmless hot-row gathers)
    int id = 0; float wl = 0.f;
    if (lane < dcap) {
        id = src_sorted[beg + lane];
        wl = rsqrt_out[id];
    }

    float acc[U][8];
#pragma unroll
    for (int u = 0; u < U; ++u)
#pragma unroll
        for (int c = 0; c < 8; ++c) acc[u][c] = 0.f;

    const ushort* base = (const ushort*)xwcat + sl * 8;

    for (int e0 = 0; e0 < dcap; e0 += G * U) {
#pragma unroll
        for (int u = 0; u < U; ++u) {
            int e = e0 + u * G + g;
            int s = __shfl(id, e & 63, 64);
            float w = __shfl(wl, e & 63, 64);
            if (e >= dcap) w = 0.f;
            uint4 q = *(const uint4*)(base + (size_t)s * C2);
            acc[u][0] += w * bflo(q.x); acc[u][1] += w * bfhi(q.x);
            acc[u][2] += w * bflo(q.y); acc[u][3] += w * bfhi(q.y);
            acc[u][4] += w * bflo(q.z); acc[u][5] += w * bfhi(q.z);
            acc[u][6] += w * bflo(q.w); acc[u][7] += w * bfhi(q.w);
        }
    }
    // rare tail: deg > 64
    for (int j = beg + 64 + g; j < end; j += G) {
        int s = src_sorted[j];
        float w = rsqrt_out[s];
        uint4 q = *(const uint4*)(base + (size_t)s * C2);
        acc[0][0] += w * bflo(q.x); acc[0][1] += w * bfhi(q.x);
        acc[0][2] += w * bflo(q.y); acc[0][3] += w * bfhi(q.y);
        acc[0][4] += w * bflo(q.z); acc[0][5] += w * bfhi(q.z);
        acc[0][6] += w * bflo(q.w); acc[0][7] += w * bfhi(q.w);
    }

#pragma unroll
    for (int c = 0; c < 8; ++c) acc[0][c] = (acc[0][c] + acc[1][c]) + (acc[2][c] + acc[3][c]);
    // reduce across groups: lanes [0,L) end with full sums
#pragma unroll
    for (int d = 32; d >= L; d >>= 1) {
#pragma unroll
        for (int c = 0; c < 8; ++c) acc[0][c] += __shfl_down(acc[0][c], d, 64);
    }

    if (lane < L) {
        float sc = (deg > 0) ? rsqrtf((float)deg) : 0.f;
        const ushort* lwp = (const ushort*)xwcat + (size_t)v * C2 + D + sl * 8;
        uint4 ql = *(const uint4*)lwp;
        const float* bp = bias + sl * 8;
        float4 b0 = *(const float4*)bp, b1 = *(const float4*)(bp + 4);
        float h[8];
        h[0] = acc[0][0] * sc + bflo(ql.x) + b0.x;
        h[1] = acc[0][1] * sc + bfhi(ql.x) + b0.y;
        h[2] = acc[0][2] * sc + bflo(ql.y) + b0.z;
        h[3] = acc[0][3] * sc + bfhi(ql.y) + b0.w;
        h[4] = acc[0][4] * sc + bflo(ql.z) + b1.x;
        h[5] = acc[0][5] * sc + bfhi(ql.z) + b1.y;
        h[6] = acc[0][6] * sc + bflo(ql.w) + b1.z;
        h[7] = acc[0][7] * sc + bfhi(ql.w) + b1.w;
        if (ACT == 1) {
            union { bf16 hh[8]; uint4 u; } o;
#pragma unroll
            for (int c = 0; c < 8; ++c) o.hh[c] = __float2bfloat16(fmaxf(h[c], 0.f));
            *(uint4*)((ushort*)out + (size_t)v * D + sl * 8) = o.u;
        } else {
            float r[8];
#pragma unroll
            for (int c = 0; c < 8; ++c) r[c] = 1.f / (1.f + expf(-h[c]));
            float* op = (float*)out + (size_t)v * D + sl * 8;
            *(float4*)op = (float4){r[0], r[1], r[2], r[3]};
            *(float4*)(op + 4) = (float4){r[4], r[5], r[6], r[7]};
        }
    }
}

// ---------------- fused MFMA GEMM: A[N,256] @ Bcat[256,C2] -> bf16 xwcat ----------------
template<int C2, bool A_BF16>
__global__ __launch_bounds__(256) void k_gemm_fused(const void* __restrict__ Aptr,
                                                    const bf16* __restrict__ B,
                                                    bf16* __restrict__ Out) {
    __shared__ bf16 As[64][40];
    __shared__ bf16 Bs[128][40];
    const int R = NNODES;
    int t = threadIdx.x;
    int wave = t >> 6, lane = t & 63;
    int r0 = blockIdx.x * 64;
    int n0 = blockIdx.y * 128;

    f4v acc[8];
#pragma unroll
    for (int i = 0; i < 8; ++i) acc[i] = (f4v){0.f, 0.f, 0.f, 0.f};

    int arow = t >> 2, aseg = t & 3;
    int bn = t & 127, bhalf = t >> 7;

    for (int k0 = 0; k0 < 256; k0 += 32) {
        {
            union { bf16 h[8]; uint4 v; } u;
            int gr = r0 + arow;
            if (gr < R) {
                if (A_BF16) {
                    const bf16* Ab = (const bf16*)Aptr;
                    u.v = *(const uint4*)(Ab + (size_t)gr * 256 + k0 + aseg * 8);
                } else {
                    const float* Af = (const float*)Aptr;
                    const float4* p = (const float4*)(Af + (size_t)gr * 256 + k0 + aseg * 8);
                    float4 f0 = p[0], f1 = p[1];
                    u.h[0] = __float2bfloat16(f0.x); u.h[1] = __float2bfloat16(f0.y);
                    u.h[2] = __float2bfloat16(f0.z); u.h[3] = __float2bfloat16(f0.w);
                    u.h[4] = __float2bfloat16(f1.x); u.h[5] = __float2bfloat16(f1.y);
                    u.h[6] = __float2bfloat16(f1.z); u.h[7] = __float2bfloat16(f1.w);
                }
            } else {
                u.v = (uint4){0, 0, 0, 0};
            }
            *(uint4*)&As[arow][aseg * 8] = u.v;
        }
        {
#pragma unroll
            for (int s8 = 0; s8 < 2; ++s8) {
                int kseg = bhalf * 2 + s8;
                union { bf16 h[8]; uint4 v; } u;
#pragma unroll
                for (int j = 0; j < 8; ++j)
                    u.h[j] = B[(size_t)(k0 + kseg * 8 + j) * C2 + n0 + bn];
                *(uint4*)&Bs[bn][kseg * 8] = u.v;
            }
        }
        __syncthreads();
        int m = wave * 16 + (lane & 15);
        int kq = (lane >> 4) * 8;
        s8v a = *(const s8v*)&As[m][kq];
#pragma unroll
        for (int nt = 0; nt < 8; ++nt) {
            s8v b = *(const s8v*)&Bs[nt * 16 + (lane & 15)][kq];
            acc[nt] = __builtin_amdgcn_mfma_f32_16x16x32_bf16(a, b, acc[nt], 0, 0, 0);
        }
        __syncthreads();
    }
#pragma unroll
    for (int nt = 0; nt < 8; ++nt) {
#pragma unroll
        for (int r = 0; r < 4; ++r) {
            int grow = r0 + wave * 16 + (lane >> 4) * 4 + r;
            int gcol = n0 + nt * 16 + (lane & 15);
            if (grow < R)
                Out[(size_t)grow * C2 + gcol] = __float2bfloat16(acc[nt][r]);
        }
    }
}

// ---------------- launcher ----------------

extern "C" void kernel_launch(void* const* d_in, const int* in_sizes, int n_in,
                              void* d_out, int out_size, void* d_ws, size_t ws_size,
                              hipStream_t stream) {
    const float* x   = (const float*)d_in[0];
    const int*   ei  = (const int*)d_in[1];
    const float* w1  = (const float*)d_in[3];
    const float* lw1 = (const float*)d_in[4];
    const float* lb1 = (const float*)d_in[5];
    const float* w2  = (const float*)d_in[6];
    const float* lw2 = (const float*)d_in[7];
    const float* lb2 = (const float*)d_in[8];
    const float* w3  = (const float*)d_in[9];
    const float* lw3 = (const float*)d_in[10];
    const float* lb3 = (const float*)d_in[11];
    float* out = (float*)d_out;

    char* ws = (char*)d_ws;
    size_t off = 0;
    auto alloc = [&](size_t bytes) -> void* {
        void* p = ws + off;
        off += (bytes + 255) & ~(size_t)255;
        return p;
    };
    int*    in_cnt     = (int*)alloc((size_t)HBINS * 4);
    float*  rsqrt_out  = (float*)alloc((size_t)HBINS * 4);
    int*    offsets    = (int*)alloc((size_t)(NNODES + 1) * 4);
    int*    cursor     = (int*)alloc((size_t)NNODES * 4);
    int*    block_sums = (int*)alloc((size_t)256 * 4);
    int*    block_base = (int*)alloc((size_t)256 * 4);
    ushort* partials   = (ushort*)alloc((size_t)2 * HNB * HBINS * 2);
    int*    src_sorted = (int*)alloc((size_t)NEDGES * 4);
    bf16*   wcat1      = (bf16*)alloc((size_t)256 * 512 * 2);
    bf16*   wcat2      = (bf16*)alloc((size_t)256 * 512 * 2);
    bf16*   wcat3      = (bf16*)alloc((size_t)256 * 256 * 2);
    bf16*   xwcat      = (bf16*)alloc((size_t)NNODES * 512 * 2);
    bf16*   h1         = (bf16*)alloc((size_t)NNODES * 256 * 2);
    bf16*   h2         = (bf16*)alloc((size_t)NNODES * 256 * 2);

    // pack weights -> bf16 [W | LW]
    k_packb<<<512, 256, 0, stream>>>(w1, lw1, wcat1, 256, 256);
    k_packb<<<512, 256, 0, stream>>>(w2, lw2, wcat2, 256, 256);
    k_packb<<<256, 256, 0, stream>>>(w3, lw3, wcat3, 256, 128);

    // graph preprocessing: LDS histograms -> reduce -> scan -> scatter
    k_hist<<<dim3(HNB, 2), 256, 0, stream>>>(ei, partials);
    k_hist_reduce<<<dim3(SCAN_NB, 2), 256, 0, stream>>>(partials, rsqrt_out, in_cnt, block_sums);
    k_scan_blocks<<<1, 256, 0, stream>>>(block_sums, block_base, SCAN_NB);
    k_scan_final<<<SCAN_NB, 256, 0, stream>>>(in_cnt, block_base, offsets, cursor);
    int eblocks = (NEDGES + 255) / 256;
    k_scatter<<<eblocks, 256, 0, stream>>>(ei, cursor, src_sorted);

    int gx = (NNODES + 63) / 64;  // 782

    // layer 1
    k_gemm_fused<512, false><<<dim3(gx, 4), 256, 0, stream>>>(x, wcat1, xwcat);
    k_agg_fused<256, 512, 1><<<NNODES, 64, 0, stream>>>(xwcat, offsets, src_sorted, rsqrt_out, lb1, h1);
    // layer 2
    k_gemm_fused<512, true><<<dim3(gx, 4), 256, 0, stream>>>(h1, wcat2, xwcat);
    k_agg_fused<256, 512, 1><<<NNODES, 64, 0, stream>>>(xwcat, offsets, src_sorted, rsqrt_out, lb2, h2);
    // layer 3
    k_gemm_fused<256, true><<<dim3(gx, 2), 256, 0, stream>>>(h2, wcat3, xwcat);
    k_agg_fused<128, 256, 2><<<NNODES, 64, 0, stream>>>(xwcat, offsets, src_sorted, rsqrt_out, lb3, out);
}